// Round 1
// baseline (907.158 us; speedup 1.0000x reference)
//
#include <hip/hip_runtime.h>
#include <math.h>

#define B_  32
#define C_  64
#define L_  2048
#define DK_ 50
#define DP_ 52   // padded K/Q row stride (floats); 52/4=13 odd -> conflict-free b128
#define VP_ 68   // padded V/P row stride in LDS; 68/4=17 odd

// Robust scalar read: works whether sample_len arrives as int32 or float32.
__device__ inline float scalar_as_float(const int* p) {
    int v = *p;
    return (v > 0 && v < (1 << 23)) ? (float)v : __int_as_float(v);
}

// -------------------- Kernel 1: projections --------------------
// K[b,l,0:50] = elu(x^T Wk + bk), pads 50..51 = 0
// Q[b,l,0:50] = elu(x^T Wq + bq) * scale (scale folded here once), pads = 0
// V[b,l,0:64] = tanh(x^T Wv + bv)
__global__ __launch_bounds__(256)
void kqv_kernel(const float* __restrict__ x,
                const float* __restrict__ Wk, const float* __restrict__ bk,
                const float* __restrict__ Wq, const float* __restrict__ bq,
                const float* __restrict__ Wv, const float* __restrict__ bv,
                const int* __restrict__ slen,
                float* __restrict__ Kw, float* __restrict__ Qw, float* __restrict__ Vw)
{
    __shared__ float xs[64][64];      // [c][l], 2-way bank alias is free
    __shared__ float wks[64 * 50];
    __shared__ float wqs[64 * 50];
    __shared__ float wvs[64 * 64];
    __shared__ float bks[50], bqs[50], bvs[64];

    const int t  = threadIdx.x;
    const int b  = blockIdx.y;
    const int l0 = blockIdx.x * 64;
    const int li = t & 63;
    const int g  = t >> 6;   // wave id 0..3, uniform per wave

    for (int c = g; c < 64; c += 4)
        xs[c][li] = x[((size_t)b * 64 + c) * L_ + l0 + li];
    for (int i = t; i < 64 * 50; i += 256) { wks[i] = Wk[i]; wqs[i] = Wq[i]; }
    for (int i = t; i < 64 * 64; i += 256) wvs[i] = Wv[i];
    if (t < 50) { bks[t] = bk[t]; bqs[t] = bq[t]; }
    if (t < 64) bvs[t] = bv[t];
    __syncthreads();

    const float scale = rsqrtf(scalar_as_float(slen));
    const int l = l0 + li;
    const size_t baseKQ = ((size_t)b * L_ + l) * DP_;
    const size_t baseV  = ((size_t)b * L_ + l) * 64;

    // 164 outputs = 41 iterations x 4 waves; j uniform per wave (no divergence)
    #pragma unroll 1
    for (int it = 0; it < 41; ++it) {
        const int j = g + 4 * it;
        float acc;
        if (j < 50) {
            acc = bks[j];
            #pragma unroll
            for (int c = 0; c < 64; ++c) acc = fmaf(xs[c][li], wks[c * 50 + j], acc);
            acc = acc > 0.f ? acc : expm1f(acc);
            Kw[baseKQ + j] = acc;
        } else if (j < 100) {
            const int jj = j - 50;
            acc = bqs[jj];
            #pragma unroll
            for (int c = 0; c < 64; ++c) acc = fmaf(xs[c][li], wqs[c * 50 + jj], acc);
            acc = acc > 0.f ? acc : expm1f(acc);
            Qw[baseKQ + jj] = acc * scale;
        } else {
            const int jj = j - 100;
            acc = bvs[jj];
            #pragma unroll
            for (int c = 0; c < 64; ++c) acc = fmaf(xs[c][li], wvs[c * 64 + jj], acc);
            Vw[baseV + jj] = tanhf(acc);
        }
    }
    if (g < 2) { Kw[baseKQ + 50 + g] = 0.f; Qw[baseKQ + 50 + g] = 0.f; }
}

// -------------------- Kernel 2: softmax denominators --------------------
// Zw[b,m] = 1 / sum_l exp(q[m]·k[l])   (scale already folded into Q; scores
// bounded |s|<~4 so no max-subtraction needed, exp can't overflow)
__global__ __launch_bounds__(256)
void zsum_kernel(const float* __restrict__ Kw, const float* __restrict__ Qw,
                 float* __restrict__ Zw)
{
    __shared__ __align__(16) float qs[32 * DP_];    // 32 m rows
    __shared__ __align__(16) float ks[128 * DP_];   // 128 l rows per chunk

    const int t  = threadIdx.x;
    const int b  = blockIdx.y;
    const int m0 = blockIdx.x * 32;
    const int mt = t >> 5;   // 0..7  (4 m rows each)
    const int lt = t & 31;   // l lane; this thread's l's are lt+{0,32,64,96}

    {
        const float4* Qg = (const float4*)(Qw + ((size_t)b * L_ + m0) * DP_);
        float4* qs4 = (float4*)qs;
        for (int i = t; i < 32 * 13; i += 256) qs4[i] = Qg[i];  // rows contiguous
    }

    float z[4] = {0.f, 0.f, 0.f, 0.f};

    for (int ch = 0; ch < 16; ++ch) {
        __syncthreads();
        {
            const float4* Kg = (const float4*)(Kw + ((size_t)b * L_ + ch * 128) * DP_);
            float4* ks4 = (float4*)ks;
            for (int i = t; i < 128 * 13; i += 256) ks4[i] = Kg[i];
        }
        __syncthreads();

        float s[4][4];
        #pragma unroll
        for (int i = 0; i < 4; ++i)
            #pragma unroll
            for (int j = 0; j < 4; ++j) s[i][j] = 0.f;

        #pragma unroll
        for (int d = 0; d < 13; ++d) {
            float4 q4[4], k4[4];
            #pragma unroll
            for (int i = 0; i < 4; ++i)
                q4[i] = *(const float4*)&qs[(mt * 4 + i) * DP_ + d * 4];  // broadcast
            #pragma unroll
            for (int j = 0; j < 4; ++j)
                k4[j] = *(const float4*)&ks[(lt + 32 * j) * DP_ + d * 4]; // stride-1 rows, 13-odd stride
            #pragma unroll
            for (int i = 0; i < 4; ++i)
                #pragma unroll
                for (int j = 0; j < 4; ++j) {
                    s[i][j] = fmaf(q4[i].x, k4[j].x, s[i][j]);
                    s[i][j] = fmaf(q4[i].y, k4[j].y, s[i][j]);
                    s[i][j] = fmaf(q4[i].z, k4[j].z, s[i][j]);
                    s[i][j] = fmaf(q4[i].w, k4[j].w, s[i][j]);
                }
        }
        #pragma unroll
        for (int i = 0; i < 4; ++i)
            #pragma unroll
            for (int j = 0; j < 4; ++j)
                z[i] += __expf(s[i][j]);
    }

    // reduce over the 32 lanes sharing mt (xor <=16 stays within half-wave)
    #pragma unroll
    for (int off = 16; off >= 1; off >>= 1)
        #pragma unroll
        for (int i = 0; i < 4; ++i)
            z[i] += __shfl_xor(z[i], off, 64);

    if (lt == 0) {
        #pragma unroll
        for (int i = 0; i < 4; ++i)
            Zw[(size_t)b * L_ + m0 + mt * 4 + i] = 1.f / z[i];  // store reciprocal
    }
}

// -------------------- Kernel 3: output --------------------
// y[b,l,c] = sum_m exp(q[m]·k[l]) * Zw[b,m] * v[m,c]
__global__ __launch_bounds__(256)
void out_kernel(const float* __restrict__ Kw, const float* __restrict__ Qw,
                const float* __restrict__ Vw, const float* __restrict__ Zw,
                float* __restrict__ out)
{
    __shared__ __align__(16) float ks[64 * DP_];   // 64 l rows (this block's output rows)
    __shared__ __align__(16) float qs[32 * DP_];   // m chunk
    __shared__ __align__(16) float vs[32 * VP_];   // m chunk
    __shared__ __align__(16) float ps[32 * VP_];   // p[m][l] for this chunk
    __shared__ float Zs[32];

    const int t  = threadIdx.x;
    const int b  = blockIdx.y;
    const int l0 = blockIdx.x * 64;

    // phase A mapping: s tile 32m x 64l; thread = 4m x 2l (l = ltA + 32j)
    const int mtA = t >> 5;   // 0..7
    const int ltA = t & 31;
    // phase B mapping: y tile 64l x 64c; thread = 4l x 4c, c fastest for coalesced stores
    const int ltB = t >> 4;   // 0..15
    const int ctB = t & 15;

    {
        const float4* Kg = (const float4*)(Kw + ((size_t)b * L_ + l0) * DP_);
        float4* ks4 = (float4*)ks;
        for (int i = t; i < 64 * 13; i += 256) ks4[i] = Kg[i];
    }

    float acc[4][4];
    #pragma unroll
    for (int i = 0; i < 4; ++i)
        #pragma unroll
        for (int j = 0; j < 4; ++j) acc[i][j] = 0.f;

    for (int ch = 0; ch < 64; ++ch) {
        __syncthreads();   // prev phase B done reading ps/vs
        {
            const float4* Qg = (const float4*)(Qw + ((size_t)b * L_ + ch * 32) * DP_);
            float4* qs4 = (float4*)qs;
            for (int i = t; i < 32 * 13; i += 256) qs4[i] = Qg[i];
            const float4* Vg = (const float4*)(Vw + ((size_t)b * L_ + ch * 32) * 64);
            float4* vs4 = (float4*)vs;
            for (int i = t; i < 32 * 16; i += 256) {
                int r = i >> 4, f = i & 15;
                vs4[r * 17 + f] = Vg[i];
            }
            if (t < 32) Zs[t] = Zw[(size_t)b * L_ + ch * 32 + t];
        }
        __syncthreads();

        // phase A: scores for m = mtA*4+i, l = ltA + 32*j
        float s[4][2];
        #pragma unroll
        for (int i = 0; i < 4; ++i) { s[i][0] = 0.f; s[i][1] = 0.f; }

        #pragma unroll
        for (int d = 0; d < 13; ++d) {
            float4 q4[4], k4[2];
            #pragma unroll
            for (int i = 0; i < 4; ++i)
                q4[i] = *(const float4*)&qs[(mtA * 4 + i) * DP_ + d * 4];
            #pragma unroll
            for (int j = 0; j < 2; ++j)
                k4[j] = *(const float4*)&ks[(ltA + 32 * j) * DP_ + d * 4];
            #pragma unroll
            for (int i = 0; i < 4; ++i)
                #pragma unroll
                for (int j = 0; j < 2; ++j) {
                    s[i][j] = fmaf(q4[i].x, k4[j].x, s[i][j]);
                    s[i][j] = fmaf(q4[i].y, k4[j].y, s[i][j]);
                    s[i][j] = fmaf(q4[i].z, k4[j].z, s[i][j]);
                    s[i][j] = fmaf(q4[i].w, k4[j].w, s[i][j]);
                }
        }
        #pragma unroll
        for (int i = 0; i < 4; ++i) {
            const float zr = Zs[mtA * 4 + i];   // reciprocal, broadcast
            #pragma unroll
            for (int j = 0; j < 2; ++j)
                ps[(mtA * 4 + i) * VP_ + ltA + 32 * j] = __expf(s[i][j]) * zr;
        }
        __syncthreads();

        // phase B: rank-32 update of the 64x64 y tile
        #pragma unroll 4
        for (int mm = 0; mm < 32; ++mm) {
            const float4 p4 = *(const float4*)&ps[mm * VP_ + ltB * 4];
            const float4 v4 = *(const float4*)&vs[mm * VP_ + ctB * 4];
            const float pv[4] = {p4.x, p4.y, p4.z, p4.w};
            const float vv[4] = {v4.x, v4.y, v4.z, v4.w};
            #pragma unroll
            for (int i = 0; i < 4; ++i)
                #pragma unroll
                for (int j = 0; j < 4; ++j)
                    acc[i][j] = fmaf(pv[i], vv[j], acc[i][j]);
        }
    }

    #pragma unroll
    for (int i = 0; i < 4; ++i) {
        float4 o = make_float4(acc[i][0], acc[i][1], acc[i][2], acc[i][3]);
        *(float4*)&out[((size_t)b * L_ + l0 + ltB * 4 + i) * 64 + ctB * 4] = o;
    }
}

extern "C" void kernel_launch(void* const* d_in, const int* in_sizes, int n_in,
                              void* d_out, int out_size, void* d_ws, size_t ws_size,
                              hipStream_t stream)
{
    const float* x  = (const float*)d_in[0];
    const float* Wk = (const float*)d_in[1];
    const float* bk = (const float*)d_in[2];
    const float* Wq = (const float*)d_in[3];
    const float* bq = (const float*)d_in[4];
    const float* Wv = (const float*)d_in[5];
    const float* bv = (const float*)d_in[6];
    const int* slen = (const int*)d_in[7];
    float* out = (float*)d_out;

    // workspace layout (44.3 MB total)
    float* Kw = (float*)d_ws;                       // B*L*52
    float* Qw = Kw + (size_t)B_ * L_ * DP_;         // B*L*52
    float* Vw = Qw + (size_t)B_ * L_ * DP_;         // B*L*64
    float* Zw = Vw + (size_t)B_ * L_ * 64;          // B*L (reciprocal denominators)

    kqv_kernel<<<dim3(L_ / 64, B_), 256, 0, stream>>>(x, Wk, bk, Wq, bq, Wv, bv, slen, Kw, Qw, Vw);
    zsum_kernel<<<dim3(L_ / 32, B_), 256, 0, stream>>>(Kw, Qw, Zw);
    out_kernel<<<dim3(L_ / 64, B_), 256, 0, stream>>>(Kw, Qw, Vw, Zw, out);
}

// Round 4
// 313.794 us; speedup vs baseline: 2.8909x; 2.8909x over previous
//
#include <hip/hip_runtime.h>
#include <math.h>

#define B_  32
#define L_  2048
#define D_  64      // padded head dim (50 -> 64)
#define LOG2E 1.44269504088896340736f

typedef unsigned short u16;
typedef float f32x4 __attribute__((ext_vector_type(4)));
typedef short s16x8 __attribute__((ext_vector_type(8)));
typedef unsigned short u16x4v __attribute__((ext_vector_type(4)));

__device__ inline float scalar_as_float(const int* p) {
    int v = *p;
    return (v > 0 && v < (1 << 23)) ? (float)v : __int_as_float(v);
}

__device__ inline float fexp2(float x) {
#if __has_builtin(__builtin_amdgcn_exp2f)
    return __builtin_amdgcn_exp2f(x);
#else
    return exp2f(x);
#endif
}

__device__ inline u16 f2bf_rne(float f) {
    unsigned int u = __float_as_uint(f);
    u += 0x7fffu + ((u >> 16) & 1u);
    return (u16)(u >> 16);
}

// x = hi + lo; hi = truncate-to-bf16 (exact residual), lo = RNE bf16 of residual
__device__ inline void bfsplit(float x, u16& h, u16& l) {
    unsigned int u = __float_as_uint(x);
    h = (u16)(u >> 16);
    l = f2bf_rne(x - __uint_as_float(u & 0xffff0000u));
}

__device__ inline f32x4 mfma16(s16x8 a, s16x8 b, f32x4 c) {
    return __builtin_amdgcn_mfma_f32_16x16x32_bf16(a, b, c, 0, 0, 0);
}

// -------------------- Kernel 1: projections -> bf16 --------------------
// Khi/Klo, Qhi/Qlo [b][l][64] split-bf16 (elu; Q scaled by scale*log2e; d>=50 = 0)
// Vthi[b][c][m] bf16-RNE (tanh; transposed for the PV B-operand)
__device__ inline void matvec16(const float (*xs)[64], const float* ws,
                                const float* bsh, int r, int sg, float* acc)
{
    #pragma unroll
    for (int jj = 0; jj < 16; ++jj) acc[jj] = bsh[sg * 16 + jj];
    #pragma unroll 4
    for (int c = 0; c < 64; ++c) {
        const float xv = xs[c][r];
        const f32x4* wr = (const f32x4*)(ws + c * 64 + sg * 16);
        #pragma unroll
        for (int q = 0; q < 4; ++q) {
            const f32x4 w = wr[q];
            #pragma unroll
            for (int i = 0; i < 4; ++i)
                acc[q * 4 + i] = fmaf(xv, w[i], acc[q * 4 + i]);
        }
    }
}

__global__ __launch_bounds__(256)
void kqv_kernel(const float* __restrict__ x,
                const float* __restrict__ Wk, const float* __restrict__ bk,
                const float* __restrict__ Wq, const float* __restrict__ bq,
                const float* __restrict__ Wv, const float* __restrict__ bv,
                const int* __restrict__ slen,
                u16* __restrict__ Khi, u16* __restrict__ Klo,
                u16* __restrict__ Qhi, u16* __restrict__ Qlo,
                u16* __restrict__ Vthi)
{
    __shared__ __align__(16) float xs[64][64];
    __shared__ __align__(16) float ws[64 * 64];
    __shared__ __align__(16) float vt[64 * 68];   // fp32 V transpose, stride 68
    __shared__ __align__(16) float bsh[64];

    const int t  = threadIdx.x;
    const int b  = blockIdx.y;
    const int l0 = blockIdx.x * 64;
    const int li = t & 63;
    const int g  = t >> 6;
    const int r  = t >> 2;     // l-row for K/Q phases
    const int sg = t & 3;      // 16-channel segment

    for (int c = g; c < 64; c += 4)
        xs[c][li] = x[((size_t)b * 64 + c) * L_ + l0 + li];

    const float sc2 = rsqrtf(scalar_as_float(slen)) * LOG2E;
    float acc[16];

    // ---- phase K ----
    for (int i = t; i < 4096; i += 256) {
        int cc = i >> 6, j = i & 63;
        ws[i] = (j < 50) ? Wk[cc * 50 + j] : 0.f;
    }
    if (t < 64) bsh[t] = (t < 50) ? bk[t] : 0.f;
    __syncthreads();
    matvec16(xs, ws, bsh, r, sg, acc);
    {
        union { u16 s[16]; uint4 v[2]; } H, Lo;
        #pragma unroll
        for (int jj = 0; jj < 16; ++jj) {
            float a = acc[jj];
            a = a > 0.f ? a : expm1f(a);          // elu (elu(0)=0 keeps pads 0)
            bfsplit(a, H.s[jj], Lo.s[jj]);
        }
        const size_t off = ((size_t)b * L_ + l0 + r) * D_ + sg * 16;
        *(uint4*)(Khi + off) = H.v[0];  *(uint4*)(Khi + off + 8) = H.v[1];
        *(uint4*)(Klo + off) = Lo.v[0]; *(uint4*)(Klo + off + 8) = Lo.v[1];
    }
    __syncthreads();

    // ---- phase Q ----
    for (int i = t; i < 4096; i += 256) {
        int cc = i >> 6, j = i & 63;
        ws[i] = (j < 50) ? Wq[cc * 50 + j] : 0.f;
    }
    if (t < 64) bsh[t] = (t < 50) ? bq[t] : 0.f;
    __syncthreads();
    matvec16(xs, ws, bsh, r, sg, acc);
    {
        union { u16 s[16]; uint4 v[2]; } H, Lo;
        #pragma unroll
        for (int jj = 0; jj < 16; ++jj) {
            float a = acc[jj];
            a = (a > 0.f ? a : expm1f(a)) * sc2;  // fold scale*log2e into Q
            bfsplit(a, H.s[jj], Lo.s[jj]);
        }
        const size_t off = ((size_t)b * L_ + l0 + r) * D_ + sg * 16;
        *(uint4*)(Qhi + off) = H.v[0];  *(uint4*)(Qhi + off + 8) = H.v[1];
        *(uint4*)(Qlo + off) = Lo.v[0]; *(uint4*)(Qlo + off + 8) = Lo.v[1];
    }
    __syncthreads();

    // ---- phase V ----
    for (int i = t; i < 4096; i += 256) ws[i] = Wv[i];
    if (t < 64) bsh[t] = bv[t];
    __syncthreads();
    matvec16(xs, ws, bsh, r, sg, acc);
    #pragma unroll
    for (int jj = 0; jj < 16; ++jj)
        vt[(sg * 16 + jj) * 68 + r] = tanhf(acc[jj]);   // transpose via LDS
    __syncthreads();
    {
        const int cB = t >> 2, ms = t & 3;
        const f32x4* vr = (const f32x4*)(vt + cB * 68 + ms * 16);
        union { u16 s[16]; uint4 v[2]; } H;
        #pragma unroll
        for (int q = 0; q < 4; ++q) {
            const f32x4 v4 = vr[q];
            #pragma unroll
            for (int i = 0; i < 4; ++i) H.s[q * 4 + i] = f2bf_rne(v4[i]);
        }
        const size_t off = ((size_t)b * 64 + cB) * L_ + l0 + ms * 16;
        *(uint4*)(Vthi + off) = H.v[0];  *(uint4*)(Vthi + off + 8) = H.v[1];
    }
}

// -------------------- Kernel 2: logZr[b][m] = -log2(sum_l 2^(k_l . q_m)) ----
__global__ __launch_bounds__(256)
void zsum_kernel(const u16* __restrict__ Khi, const u16* __restrict__ Klo,
                 const u16* __restrict__ Qhi, const u16* __restrict__ Qlo,
                 float* __restrict__ logZr)
{
    __shared__ __align__(16) u16 kh_s[64 * 72];
    __shared__ __align__(16) u16 kl_s[64 * 72];

    const int t = threadIdx.x;
    const int b = blockIdx.y;
    const int m0 = blockIdx.x * 64;
    const int wave = t >> 6;
    const int lane = t & 63;
    const int l15 = lane & 15;
    const int quad = lane >> 4;
    const int r = t >> 2, sg = t & 3;

    // A-operand (Q) rows m = m0 + wave*16 + l15, kept in registers
    const size_t qrow = ((size_t)b * L_ + m0 + wave * 16 + l15) * D_;
    const s16x8 qh0 = *(const s16x8*)(Qhi + qrow + quad * 8);
    const s16x8 qh1 = *(const s16x8*)(Qhi + qrow + 32 + quad * 8);
    const s16x8 ql0 = *(const s16x8*)(Qlo + qrow + quad * 8);
    const s16x8 ql1 = *(const s16x8*)(Qlo + qrow + 32 + quad * 8);

    float zacc[4] = {0.f, 0.f, 0.f, 0.f};

    for (int ch = 0; ch < 32; ++ch) {
        __syncthreads();
        {
            const size_t krow = ((size_t)b * L_ + ch * 64 + r) * D_ + sg * 16;
            const int lo = r * 72 + sg * 16;
            // 16 u16 per thread -> TWO uint4 stores (the round-2/3 bug: only one)
            *(uint4*)(kh_s + lo)     = *(const uint4*)(Khi + krow);
            *(uint4*)(kh_s + lo + 8) = *(const uint4*)(Khi + krow + 8);
            *(uint4*)(kl_s + lo)     = *(const uint4*)(Klo + krow);
            *(uint4*)(kl_s + lo + 8) = *(const uint4*)(Klo + krow + 8);
        }
        __syncthreads();
        #pragma unroll
        for (int lt = 0; lt < 4; ++lt) {
            const int koff = (lt * 16 + l15) * 72 + quad * 8;
            const s16x8 bh0 = *(const s16x8*)(kh_s + koff);
            const s16x8 bh1 = *(const s16x8*)(kh_s + koff + 32);
            const s16x8 bl0 = *(const s16x8*)(kl_s + koff);
            const s16x8 bl1 = *(const s16x8*)(kl_s + koff + 32);
            f32x4 s = {0.f, 0.f, 0.f, 0.f};
            s = mfma16(qh0, bh0, s);
            s = mfma16(qh1, bh1, s);
            s = mfma16(qh0, bl0, s);
            s = mfma16(qh1, bl1, s);
            s = mfma16(ql0, bh0, s);
            s = mfma16(ql1, bh1, s);
            #pragma unroll
            for (int i = 0; i < 4; ++i) zacc[i] += fexp2(fminf(s[i], 80.f));
        }
    }

    #pragma unroll
    for (int off = 1; off < 16; off <<= 1)
        #pragma unroll
        for (int i = 0; i < 4; ++i)
            zacc[i] += __shfl_xor(zacc[i], off, 64);

    if (l15 == 0) {
        f32x4 nl;
        #pragma unroll
        for (int i = 0; i < 4; ++i) nl[i] = -log2f(fmaxf(zacc[i], 1e-37f));
        *(f32x4*)(logZr + (size_t)b * L_ + m0 + wave * 16 + quad * 4) = nl;
    }
}

// -------------------- Kernel 3: y[l][c] = sum_m 2^(s[m][l]-log2 Z[m]) v[m][c]
__global__ __launch_bounds__(256)
void out_kernel(const u16* __restrict__ Khi, const u16* __restrict__ Klo,
                const u16* __restrict__ Qhi, const u16* __restrict__ Qlo,
                const u16* __restrict__ Vthi,
                const float* __restrict__ logZr,
                float* __restrict__ out)
{
    __shared__ __align__(16) u16 qh_s[64 * 72], ql_s[64 * 72];
    __shared__ __align__(16) u16 vh_s[64 * 72];
    __shared__ __align__(16) u16 ph_s[4 * 16 * 72], pl_s[4 * 16 * 72];  // per-wave

    const int t = threadIdx.x;
    const int b = blockIdx.y;
    const int l0 = blockIdx.x * 64;
    const int wave = t >> 6;
    const int lane = t & 63;
    const int l15 = lane & 15;
    const int quad = lane >> 4;
    const int r = t >> 2, sg = t & 3;
    const int pbase = wave * 16 * 72;

    // K fragments (B-operand of scores): rows l = l0 + wave*16 + l15, in regs
    const size_t krow = ((size_t)b * L_ + l0 + wave * 16 + l15) * D_;
    const s16x8 kh0 = *(const s16x8*)(Khi + krow + quad * 8);
    const s16x8 kh1 = *(const s16x8*)(Khi + krow + 32 + quad * 8);
    const s16x8 kl0 = *(const s16x8*)(Klo + krow + quad * 8);
    const s16x8 kl1 = *(const s16x8*)(Klo + krow + 32 + quad * 8);

    f32x4 acc[4];
    #pragma unroll
    for (int ct = 0; ct < 4; ++ct) acc[ct] = (f32x4){0.f, 0.f, 0.f, 0.f};

    for (int ch = 0; ch < 32; ++ch) {
        const int m0 = ch * 64;
        __syncthreads();            // previous chunk's LDS reads done
        {
            const size_t qrow = ((size_t)b * L_ + m0 + r) * D_ + sg * 16;
            const size_t vrow = ((size_t)b * 64 + r) * L_ + m0 + sg * 16;
            const int lo = r * 72 + sg * 16;
            // 16 u16 per thread -> TWO uint4 stores each (bug fix)
            *(uint4*)(qh_s + lo)     = *(const uint4*)(Qhi + qrow);
            *(uint4*)(qh_s + lo + 8) = *(const uint4*)(Qhi + qrow + 8);
            *(uint4*)(ql_s + lo)     = *(const uint4*)(Qlo + qrow);
            *(uint4*)(ql_s + lo + 8) = *(const uint4*)(Qlo + qrow + 8);
            *(uint4*)(vh_s + lo)     = *(const uint4*)(Vthi + vrow);
            *(uint4*)(vh_s + lo + 8) = *(const uint4*)(Vthi + vrow + 8);
        }
        __syncthreads();

        // scores S[m][l] for 4 m-tiles; C seeded with -log2(Z[m])
        #pragma unroll
        for (int mt = 0; mt < 4; ++mt) {
            f32x4 s = *(const f32x4*)(logZr + (size_t)b * L_ + m0 + mt * 16 + quad * 4);
            const int qoff = (mt * 16 + l15) * 72 + quad * 8;
            const s16x8 ah0 = *(const s16x8*)(qh_s + qoff);
            const s16x8 ah1 = *(const s16x8*)(qh_s + qoff + 32);
            const s16x8 al0 = *(const s16x8*)(ql_s + qoff);
            const s16x8 al1 = *(const s16x8*)(ql_s + qoff + 32);
            s = mfma16(ah0, kh0, s);
            s = mfma16(ah1, kh1, s);
            s = mfma16(ah0, kl0, s);
            s = mfma16(ah1, kl1, s);
            s = mfma16(al0, kh0, s);
            s = mfma16(al1, kh1, s);
            u16x4v p4h, p4l;
            #pragma unroll
            for (int i = 0; i < 4; ++i) {
                const float p = fexp2(fminf(s[i], 80.f));  // normalized; inf-proof
                unsigned int u = __float_as_uint(p);
                p4h[i] = (u16)(u >> 16);
                p4l[i] = f2bf_rne(p - __uint_as_float(u & 0xffff0000u));
            }
            // P layout transform: C-layout -> A-operand layout [l][m]
            const int poff = pbase + l15 * 72 + mt * 16 + quad * 4;
            *(u16x4v*)(ph_s + poff) = p4h;
            *(u16x4v*)(pl_s + poff) = p4l;
        }
        __syncthreads();   // paranoia barrier (wave-private P; remove once green)

        // PV: rank-64 update of the wave's 16l x 64c tile (V bf16, P split)
        #pragma unroll
        for (int ks = 0; ks < 2; ++ks) {
            const int paoff = pbase + l15 * 72 + ks * 32 + quad * 8;
            const s16x8 pah = *(const s16x8*)(ph_s + paoff);
            const s16x8 pal = *(const s16x8*)(pl_s + paoff);
            #pragma unroll
            for (int ct = 0; ct < 4; ++ct) {
                const int voff = (ct * 16 + l15) * 72 + ks * 32 + quad * 8;
                const s16x8 bvh = *(const s16x8*)(vh_s + voff);
                acc[ct] = mfma16(pah, bvh, acc[ct]);
                acc[ct] = mfma16(pal, bvh, acc[ct]);
            }
        }
    }

    const int row = l0 + wave * 16 + quad * 4;
    #pragma unroll
    for (int ct = 0; ct < 4; ++ct)
        #pragma unroll
        for (int i = 0; i < 4; ++i)
            out[((size_t)b * L_ + row + i) * 64 + ct * 16 + l15] = acc[ct][i];
}

extern "C" void kernel_launch(void* const* d_in, const int* in_sizes, int n_in,
                              void* d_out, int out_size, void* d_ws, size_t ws_size,
                              hipStream_t stream)
{
    const float* x  = (const float*)d_in[0];
    const float* Wk = (const float*)d_in[1];
    const float* bk = (const float*)d_in[2];
    const float* Wq = (const float*)d_in[3];
    const float* bq = (const float*)d_in[4];
    const float* Wv = (const float*)d_in[5];
    const float* bv = (const float*)d_in[6];
    const int* slen = (const int*)d_in[7];
    float* out = (float*)d_out;

    // workspace: logZr fp32 first, then 5 bf16 arrays of B*L*64  (~40.3 MiB)
    const size_t n = (size_t)B_ * L_ * D_;
    float* logZr = (float*)d_ws;
    u16* Khi  = (u16*)(logZr + (size_t)B_ * L_);
    u16* Klo  = Khi + n;
    u16* Qhi  = Klo + n;
    u16* Qlo  = Qhi + n;
    u16* Vthi = Qlo + n;

    kqv_kernel<<<dim3(L_ / 64, B_), 256, 0, stream>>>(x, Wk, bk, Wq, bq, Wv, bv,
                                                      slen, Khi, Klo, Qhi, Qlo, Vthi);
    zsum_kernel<<<dim3(L_ / 64, B_), 256, 0, stream>>>(Khi, Klo, Qhi, Qlo, logZr);
    out_kernel<<<dim3(L_ / 64, B_), 256, 0, stream>>>(Khi, Klo, Qhi, Qlo, Vthi,
                                                      logZr, out);
}

// Round 5
// 268.233 us; speedup vs baseline: 3.3820x; 1.1699x over previous
//
#include <hip/hip_runtime.h>
#include <math.h>

#define B_  32
#define L_  2048
#define D_  64      // padded head dim (50 -> 64)
#define LOG2E 1.44269504088896340736f

typedef unsigned short u16;
typedef float f32x4 __attribute__((ext_vector_type(4)));
typedef short s16x8 __attribute__((ext_vector_type(8)));
typedef unsigned short u16x4v __attribute__((ext_vector_type(4)));

__device__ inline float scalar_as_float(const int* p) {
    int v = *p;
    return (v > 0 && v < (1 << 23)) ? (float)v : __int_as_float(v);
}

__device__ inline float fexp2(float x) {
#if __has_builtin(__builtin_amdgcn_exp2f)
    return __builtin_amdgcn_exp2f(x);
#else
    return exp2f(x);
#endif
}
__device__ inline float frcp(float x) {
#if __has_builtin(__builtin_amdgcn_rcpf)
    return __builtin_amdgcn_rcpf(x);
#else
    return 1.0f / x;
#endif
}
// elu via hw exp2: abs err ~1e-7 (fine, k/q are O(1))
__device__ inline float fast_elu(float a) {
    return a > 0.f ? a : fexp2(a * LOG2E) - 1.0f;
}
// tanh(a) = (e^{2a}-1)/(e^{2a}+1); |acc| < ~8 so no overflow; clamp for safety
__device__ inline float fast_tanh(float a) {
    a = fminf(fmaxf(a, -20.f), 20.f);
    const float t = fexp2(a * (2.0f * LOG2E));
    return (t - 1.0f) * frcp(t + 1.0f);
}

__device__ inline u16 f2bf_rne(float f) {
    unsigned int u = __float_as_uint(f);
    u += 0x7fffu + ((u >> 16) & 1u);
    return (u16)(u >> 16);
}
// x = hi + lo; hi = truncate-to-bf16 (exact residual), lo = RNE bf16 of residual
__device__ inline void bfsplit(float x, u16& h, u16& l) {
    unsigned int u = __float_as_uint(x);
    h = (u16)(u >> 16);
    l = f2bf_rne(x - __uint_as_float(u & 0xffff0000u));
}
__device__ inline f32x4 mfma16(s16x8 a, s16x8 b, f32x4 c) {
    return __builtin_amdgcn_mfma_f32_16x16x32_bf16(a, b, c, 0, 0, 0);
}

// -------------------- Kernel 1: projections -> bf16 --------------------
__device__ inline void matvec16(const float (*xs)[64], const float* ws,
                                const float* bsh, int r, int sg, float* acc)
{
    #pragma unroll
    for (int jj = 0; jj < 16; ++jj) acc[jj] = bsh[sg * 16 + jj];
    #pragma unroll 4
    for (int c = 0; c < 64; ++c) {
        const float xv = xs[c][r];
        const f32x4* wr = (const f32x4*)(ws + c * 64 + sg * 16);
        #pragma unroll
        for (int q = 0; q < 4; ++q) {
            const f32x4 w = wr[q];
            #pragma unroll
            for (int i = 0; i < 4; ++i)
                acc[q * 4 + i] = fmaf(xv, w[i], acc[q * 4 + i]);
        }
    }
}

__global__ __launch_bounds__(256)
void kqv_kernel(const float* __restrict__ x,
                const float* __restrict__ Wk, const float* __restrict__ bk,
                const float* __restrict__ Wq, const float* __restrict__ bq,
                const float* __restrict__ Wv, const float* __restrict__ bv,
                const int* __restrict__ slen,
                u16* __restrict__ Khi, u16* __restrict__ Klo,
                u16* __restrict__ Qhi, u16* __restrict__ Qlo,
                u16* __restrict__ Vthi)
{
    __shared__ __align__(16) float xs[64][64];
    __shared__ __align__(16) float ws[64 * 64];
    __shared__ __align__(16) float vt[64 * 68];
    __shared__ __align__(16) float bsh[64];

    const int t  = threadIdx.x;
    const int b  = blockIdx.y;
    const int l0 = blockIdx.x * 64;
    const int li = t & 63;
    const int g  = t >> 6;
    const int r  = t >> 2;
    const int sg = t & 3;

    for (int c = g; c < 64; c += 4)
        xs[c][li] = x[((size_t)b * 64 + c) * L_ + l0 + li];

    const float sc2 = rsqrtf(scalar_as_float(slen)) * LOG2E;
    float acc[16];

    // ---- phase K ----
    for (int i = t; i < 4096; i += 256) {
        int cc = i >> 6, j = i & 63;
        ws[i] = (j < 50) ? Wk[cc * 50 + j] : 0.f;
    }
    if (t < 64) bsh[t] = (t < 50) ? bk[t] : 0.f;
    __syncthreads();
    matvec16(xs, ws, bsh, r, sg, acc);
    {
        union { u16 s[16]; uint4 v[2]; } H, Lo;
        #pragma unroll
        for (int jj = 0; jj < 16; ++jj)
            bfsplit(fast_elu(acc[jj]), H.s[jj], Lo.s[jj]);
        const size_t off = ((size_t)b * L_ + l0 + r) * D_ + sg * 16;
        *(uint4*)(Khi + off) = H.v[0];  *(uint4*)(Khi + off + 8) = H.v[1];
        *(uint4*)(Klo + off) = Lo.v[0]; *(uint4*)(Klo + off + 8) = Lo.v[1];
    }
    __syncthreads();

    // ---- phase Q ----
    for (int i = t; i < 4096; i += 256) {
        int cc = i >> 6, j = i & 63;
        ws[i] = (j < 50) ? Wq[cc * 50 + j] : 0.f;
    }
    if (t < 64) bsh[t] = (t < 50) ? bq[t] : 0.f;
    __syncthreads();
    matvec16(xs, ws, bsh, r, sg, acc);
    {
        union { u16 s[16]; uint4 v[2]; } H, Lo;
        #pragma unroll
        for (int jj = 0; jj < 16; ++jj)
            bfsplit(fast_elu(acc[jj]) * sc2, H.s[jj], Lo.s[jj]);
        const size_t off = ((size_t)b * L_ + l0 + r) * D_ + sg * 16;
        *(uint4*)(Qhi + off) = H.v[0];  *(uint4*)(Qhi + off + 8) = H.v[1];
        *(uint4*)(Qlo + off) = Lo.v[0]; *(uint4*)(Qlo + off + 8) = Lo.v[1];
    }
    __syncthreads();

    // ---- phase V ----
    for (int i = t; i < 4096; i += 256) ws[i] = Wv[i];
    if (t < 64) bsh[t] = bv[t];
    __syncthreads();
    matvec16(xs, ws, bsh, r, sg, acc);
    #pragma unroll
    for (int jj = 0; jj < 16; ++jj)
        vt[(sg * 16 + jj) * 68 + r] = fast_tanh(acc[jj]);
    __syncthreads();
    {
        const int cB = t >> 2, ms = t & 3;
        const f32x4* vr = (const f32x4*)(vt + cB * 68 + ms * 16);
        union { u16 s[16]; uint4 v[2]; } H;
        #pragma unroll
        for (int q = 0; q < 4; ++q) {
            const f32x4 v4 = vr[q];
            #pragma unroll
            for (int i = 0; i < 4; ++i) H.s[q * 4 + i] = f2bf_rne(v4[i]);
        }
        const size_t off = ((size_t)b * 64 + cB) * L_ + l0 + ms * 16;
        *(uint4*)(Vthi + off) = H.v[0];  *(uint4*)(Vthi + off + 8) = H.v[1];
    }
}

// -------------------- Kernel 2: logZr[b][m] = -log2(sum_l 2^(k_l . q_m)) ----
__global__ __launch_bounds__(256, 4)
void zsum_kernel(const u16* __restrict__ Khi, const u16* __restrict__ Klo,
                 const u16* __restrict__ Qhi, const u16* __restrict__ Qlo,
                 float* __restrict__ logZr)
{
    __shared__ __align__(16) u16 kh_s[64 * 72];
    __shared__ __align__(16) u16 kl_s[64 * 72];

    const int t = threadIdx.x;
    const int b = blockIdx.y;
    const int m0 = blockIdx.x * 64;
    const int wave = t >> 6;
    const int lane = t & 63;
    const int l15 = lane & 15;
    const int quad = lane >> 4;
    const int r = t >> 2, sg = t & 3;

    const size_t qrow = ((size_t)b * L_ + m0 + wave * 16 + l15) * D_;
    const s16x8 qh0 = *(const s16x8*)(Qhi + qrow + quad * 8);
    const s16x8 qh1 = *(const s16x8*)(Qhi + qrow + 32 + quad * 8);
    const s16x8 ql0 = *(const s16x8*)(Qlo + qrow + quad * 8);
    const s16x8 ql1 = *(const s16x8*)(Qlo + qrow + 32 + quad * 8);

    float zacc[4] = {0.f, 0.f, 0.f, 0.f};

    // software pipeline: chunk ch staged from regs loaded during ch-1
    uint4 rk0, rk1, rk2, rk3;
    {
        const size_t krow = ((size_t)b * L_ + r) * D_ + sg * 16;
        rk0 = *(const uint4*)(Khi + krow); rk1 = *(const uint4*)(Khi + krow + 8);
        rk2 = *(const uint4*)(Klo + krow); rk3 = *(const uint4*)(Klo + krow + 8);
    }

    for (int ch = 0; ch < 32; ++ch) {
        __syncthreads();
        {
            const int lo = r * 72 + sg * 16;
            *(uint4*)(kh_s + lo)     = rk0;
            *(uint4*)(kh_s + lo + 8) = rk1;
            *(uint4*)(kl_s + lo)     = rk2;
            *(uint4*)(kl_s + lo + 8) = rk3;
        }
        __syncthreads();
        if (ch < 31) {   // prefetch next chunk while computing this one
            const size_t krow = ((size_t)b * L_ + (ch + 1) * 64 + r) * D_ + sg * 16;
            rk0 = *(const uint4*)(Khi + krow); rk1 = *(const uint4*)(Khi + krow + 8);
            rk2 = *(const uint4*)(Klo + krow); rk3 = *(const uint4*)(Klo + krow + 8);
        }
        #pragma unroll
        for (int lt = 0; lt < 4; ++lt) {
            const int koff = (lt * 16 + l15) * 72 + quad * 8;
            const s16x8 bh0 = *(const s16x8*)(kh_s + koff);
            const s16x8 bh1 = *(const s16x8*)(kh_s + koff + 32);
            const s16x8 bl0 = *(const s16x8*)(kl_s + koff);
            const s16x8 bl1 = *(const s16x8*)(kl_s + koff + 32);
            f32x4 s = {0.f, 0.f, 0.f, 0.f};
            s = mfma16(qh0, bh0, s);
            s = mfma16(qh1, bh1, s);
            s = mfma16(qh0, bl0, s);
            s = mfma16(qh1, bl1, s);
            s = mfma16(ql0, bh0, s);
            s = mfma16(ql1, bh1, s);
            #pragma unroll
            for (int i = 0; i < 4; ++i) zacc[i] += fexp2(fminf(s[i], 80.f));
        }
    }

    #pragma unroll
    for (int off = 1; off < 16; off <<= 1)
        #pragma unroll
        for (int i = 0; i < 4; ++i)
            zacc[i] += __shfl_xor(zacc[i], off, 64);

    if (l15 == 0) {
        f32x4 nl;
        #pragma unroll
        for (int i = 0; i < 4; ++i) nl[i] = -log2f(fmaxf(zacc[i], 1e-37f));
        *(f32x4*)(logZr + (size_t)b * L_ + m0 + wave * 16 + quad * 4) = nl;
    }
}

// -------------------- Kernel 3: y[l][c] = sum_m 2^(s[m][l]-log2 Z[m]) v[m][c]
__global__ __launch_bounds__(256, 3)
void out_kernel(const u16* __restrict__ Khi, const u16* __restrict__ Klo,
                const u16* __restrict__ Qhi, const u16* __restrict__ Qlo,
                const u16* __restrict__ Vthi,
                const float* __restrict__ logZr,
                float* __restrict__ out)
{
    __shared__ __align__(16) u16 qh_s[64 * 72], ql_s[64 * 72];
    __shared__ __align__(16) u16 vh_s[64 * 72];
    __shared__ __align__(16) u16 ph_s[4 * 16 * 72];   // per-wave P (bf16, no split)

    const int t = threadIdx.x;
    const int b = blockIdx.y;
    const int l0 = blockIdx.x * 64;
    const int wave = t >> 6;
    const int lane = t & 63;
    const int l15 = lane & 15;
    const int quad = lane >> 4;
    const int r = t >> 2, sg = t & 3;
    const int pbase = wave * 16 * 72;

    // K fragments (B-operand of scores): rows l = l0 + wave*16 + l15, in regs
    const size_t krow = ((size_t)b * L_ + l0 + wave * 16 + l15) * D_;
    const s16x8 kh0 = *(const s16x8*)(Khi + krow + quad * 8);
    const s16x8 kh1 = *(const s16x8*)(Khi + krow + 32 + quad * 8);
    const s16x8 kl0 = *(const s16x8*)(Klo + krow + quad * 8);
    const s16x8 kl1 = *(const s16x8*)(Klo + krow + 32 + quad * 8);

    f32x4 acc[4];
    #pragma unroll
    for (int ct = 0; ct < 4; ++ct) acc[ct] = (f32x4){0.f, 0.f, 0.f, 0.f};

    // software pipeline registers (chunk 0 prologue)
    uint4 rq0, rq1, rl0, rl1, rv0, rv1;
    {
        const size_t qrow0 = ((size_t)b * L_ + r) * D_ + sg * 16;
        const size_t vrow0 = ((size_t)b * 64 + r) * L_ + sg * 16;
        rq0 = *(const uint4*)(Qhi + qrow0); rq1 = *(const uint4*)(Qhi + qrow0 + 8);
        rl0 = *(const uint4*)(Qlo + qrow0); rl1 = *(const uint4*)(Qlo + qrow0 + 8);
        rv0 = *(const uint4*)(Vthi + vrow0); rv1 = *(const uint4*)(Vthi + vrow0 + 8);
    }

    for (int ch = 0; ch < 32; ++ch) {
        const int m0 = ch * 64;
        __syncthreads();            // previous chunk's LDS reads done
        {
            const int lo = r * 72 + sg * 16;
            *(uint4*)(qh_s + lo)     = rq0;
            *(uint4*)(qh_s + lo + 8) = rq1;
            *(uint4*)(ql_s + lo)     = rl0;
            *(uint4*)(ql_s + lo + 8) = rl1;
            *(uint4*)(vh_s + lo)     = rv0;
            *(uint4*)(vh_s + lo + 8) = rv1;
        }
        __syncthreads();

        // seeds FIRST (oldest in vmcnt order), then prefetch: seed waits
        // don't force prefetch completion
        f32x4 seed[4];
        #pragma unroll
        for (int mt = 0; mt < 4; ++mt)
            seed[mt] = *(const f32x4*)(logZr + (size_t)b * L_ + m0 + mt * 16 + quad * 4);

        if (ch < 31) {
            const size_t qrow1 = ((size_t)b * L_ + (ch + 1) * 64 + r) * D_ + sg * 16;
            const size_t vrow1 = ((size_t)b * 64 + r) * L_ + (ch + 1) * 64 + sg * 16;
            rq0 = *(const uint4*)(Qhi + qrow1); rq1 = *(const uint4*)(Qhi + qrow1 + 8);
            rl0 = *(const uint4*)(Qlo + qrow1); rl1 = *(const uint4*)(Qlo + qrow1 + 8);
            rv0 = *(const uint4*)(Vthi + vrow1); rv1 = *(const uint4*)(Vthi + vrow1 + 8);
        }

        // scores S[m][l] for 4 m-tiles; C seeded with -log2(Z[m])
        #pragma unroll
        for (int mt = 0; mt < 4; ++mt) {
            f32x4 s = seed[mt];
            const int qoff = (mt * 16 + l15) * 72 + quad * 8;
            const s16x8 ah0 = *(const s16x8*)(qh_s + qoff);
            const s16x8 ah1 = *(const s16x8*)(qh_s + qoff + 32);
            const s16x8 al0 = *(const s16x8*)(ql_s + qoff);
            const s16x8 al1 = *(const s16x8*)(ql_s + qoff + 32);
            s = mfma16(ah0, kh0, s);
            s = mfma16(ah1, kh1, s);
            s = mfma16(ah0, kl0, s);
            s = mfma16(ah1, kl1, s);
            s = mfma16(al0, kh0, s);
            s = mfma16(al1, kh1, s);
            u16x4v p4h;
            #pragma unroll
            for (int i = 0; i < 4; ++i)
                p4h[i] = f2bf_rne(fexp2(fminf(s[i], 80.f)));  // normalized P, bf16
            // P layout transform: C-layout -> A-operand layout [l][m]
            *(u16x4v*)(ph_s + pbase + l15 * 72 + mt * 16 + quad * 4) = p4h;
        }
        // ph_s is wave-private; per-wave DS ops are in-order -> no barrier

        // PV: rank-64 update of the wave's 16l x 64c tile
        #pragma unroll
        for (int ks = 0; ks < 2; ++ks) {
            const s16x8 pah = *(const s16x8*)(ph_s + pbase + l15 * 72 + ks * 32 + quad * 8);
            #pragma unroll
            for (int ct = 0; ct < 4; ++ct) {
                const s16x8 bvh = *(const s16x8*)(vh_s + (ct * 16 + l15) * 72 + ks * 32 + quad * 8);
                acc[ct] = mfma16(pah, bvh, acc[ct]);
            }
        }
    }

    const int row = l0 + wave * 16 + quad * 4;
    #pragma unroll
    for (int ct = 0; ct < 4; ++ct)
        #pragma unroll
        for (int i = 0; i < 4; ++i)
            out[((size_t)b * L_ + row + i) * 64 + ct * 16 + l15] = acc[ct][i];
}

extern "C" void kernel_launch(void* const* d_in, const int* in_sizes, int n_in,
                              void* d_out, int out_size, void* d_ws, size_t ws_size,
                              hipStream_t stream)
{
    const float* x  = (const float*)d_in[0];
    const float* Wk = (const float*)d_in[1];
    const float* bk = (const float*)d_in[2];
    const float* Wq = (const float*)d_in[3];
    const float* bq = (const float*)d_in[4];
    const float* Wv = (const float*)d_in[5];
    const float* bv = (const float*)d_in[6];
    const int* slen = (const int*)d_in[7];
    float* out = (float*)d_out;

    const size_t n = (size_t)B_ * L_ * D_;
    float* logZr = (float*)d_ws;
    u16* Khi  = (u16*)(logZr + (size_t)B_ * L_);
    u16* Klo  = Khi + n;
    u16* Qhi  = Klo + n;
    u16* Qlo  = Qhi + n;
    u16* Vthi = Qlo + n;

    kqv_kernel<<<dim3(L_ / 64, B_), 256, 0, stream>>>(x, Wk, bk, Wq, bq, Wv, bv,
                                                      slen, Khi, Klo, Qhi, Qlo, Vthi);
    zsum_kernel<<<dim3(L_ / 64, B_), 256, 0, stream>>>(Khi, Klo, Qhi, Qlo, logZr);
    out_kernel<<<dim3(L_ / 64, B_), 256, 0, stream>>>(Khi, Klo, Qhi, Qlo, Vthi,
                                                      logZr, out);
}